// Round 4
// baseline (117.624 us; speedup 1.0000x reference)
//
#include <hip/hip_runtime.h>

// RelativePositionEncoding: out[i,j,c] = W[dres][c] + W[65+dtok][c]
//                                      + same_entity*W[130][c] + W[131+dch][c]
// B=1, N=1024, CZ=128, W: [136][128] fp32. Output 512 MiB fp32 — HBM-write-bound.
// fillBuffer reference on this chip: 6.7 TB/s write -> ~80 us for 536.9 MB.
//
// R4 theory: R1-R3 all ~117us (4.6 TB/s) despite store batching — latency-bound
// at 16 waves/CU (LDS 73.7KB -> 2 blocks/CU). Fix: channel-split. Each block
// owns 64 of 128 channels, stages half of W (34.8KB + 4KB = 38.9KB LDS) ->
// 4 blocks/CU = 32 waves/CU = 8 waves/SIMD. launch_bounds(512,8) forces
// VGPR<=64 so the occupancy materializes.

typedef float f4 __attribute__((ext_vector_type(4)));

constexpr int ROWS = 136;          // 65 rel_pos | 65 rel_token | 1 entity | 5 rel_chain
constexpr int THREADS = 512;
constexpr int GRID = 1024;         // 2^19 threads; each stores 64 float4
constexpr int BATCH = 4;

__global__ __launch_bounds__(THREADS, 8)
void relpos_kernel(const int* __restrict__ asym,
                   const int* __restrict__ resid,
                   const int* __restrict__ ent,
                   const int* __restrict__ tok,
                   const int* __restrict__ sym,
                   const float* __restrict__ W,
                   f4* __restrict__ outv)
{
    __shared__ f4 sW[ROWS * 16];     // half-row per block: 136 x 16 f4 = 34,816 B
    __shared__ uint32_t sPk[1024];   // packed scalars: 4 KB (total 38.9 KB -> 4 blocks/CU)
    const int tid = threadIdx.x;

    const int t = blockIdx.x * THREADS + tid;
    const int h = t >> 18;           // 0 or 1: which 64-channel half this block owns

    // ---- stage this block's half of W (coalesced f4) + pack the 5 int arrays ----
    const f4* Wv = reinterpret_cast<const f4*>(W);   // W as [136][32] f4
    for (int k = tid; k < ROWS * 16; k += THREADS) {
        const int row = k >> 4, c = k & 15;
        sW[k] = Wv[row * 32 + h * 16 + c];
    }
    for (int k = tid; k < 1024; k += THREADS) {
        // asym 3b | resid 10b | ent 2b | tok 10b | sym 2b
        sPk[k] = (uint32_t)asym[k]
               | ((uint32_t)resid[k] << 3)
               | ((uint32_t)ent[k]   << 13)
               | ((uint32_t)tok[k]   << 15)
               | ((uint32_t)sym[k]   << 25);
    }
    __syncthreads();

    // ---- decomposition: s -> (c4 in [0,16), j fixed per thread, i0 block-uniform) ----
    const int s  = t & ((1 << 18) - 1);
    const int c4 = s & 15;
    const int p0 = s >> 4;          // in [0, 16384)
    const int j  = p0 & 1023;       // 32 consecutive j per block
    const int i0 = p0 >> 10;        // block-uniform, in [0,16); i = i0 + 16*it

    const uint32_t pkj = sPk[j];
    const int aj  = pkj & 7;
    const int rjb = ((pkj >> 3)  & 1023) + 32;
    const int ej  = (pkj >> 13) & 3;
    const int tjb = ((pkj >> 15) & 1023) + 32;
    const int sjb = ((pkj >> 25) & 3) + 2;
    const int rj  = rjb - 32;

    const f4 vE = sW[130 * 16 + c4];    // entity row hoisted

    // f4 index into out: (i*1024 + j)*32 + h*16 + c4
    size_t oidx = (size_t)p0 * 32 + (size_t)h * 16 + c4;
    for (int b = 0; b < 64 / BATCH; ++b) {
        f4 r[BATCH];
        #pragma unroll
        for (int u = 0; u < BATCH; ++u) {
            const int i = i0 + 16 * (b * BATCH + u);
            // i is block-uniform -> broadcast read + readfirstlane -> SALU unpack
            const uint32_t pkc =
                (uint32_t)__builtin_amdgcn_readfirstlane((int)sPk[i]);

            const int ai = pkc & 7;
            const int ri = (pkc >> 3)  & 1023;
            const int ei = (pkc >> 13) & 3;
            const int ti = (pkc >> 15) & 1023;
            const int si = (pkc >> 25) & 3;

            const bool sc  = (ai == aj);
            const bool scr = sc || (ri == rj);

            int dres = min(max(rjb - ri, 0), 64);
            int dtok = min(max(tjb - ti, 0), 64);
            int dch  = min(max(sjb - si, 0), 4);
            if (sc)  { dres = 64; dch = 4; }
            if (scr) { dtok = 64; }
            const float se = (ei == ej) ? 1.0f : 0.0f;

            const f4 v0 = sW[dres * 16 + c4];
            const f4 v1 = sW[(65 + dtok) * 16 + c4];
            const f4 v3 = sW[(131 + dch) * 16 + c4];

            // reference fp32 order: ((t0 + t1) + se*w130) + t3
            r[u].x = fmaf(se, vE.x, v0.x + v1.x) + v3.x;
            r[u].y = fmaf(se, vE.y, v0.y + v1.y) + v3.y;
            r[u].z = fmaf(se, vE.z, v0.z + v1.z) + v3.z;
            r[u].w = fmaf(se, vE.w, v0.w + v1.w) + v3.w;
        }
        #pragma unroll
        for (int u = 0; u < BATCH; ++u) {
            outv[oidx] = r[u];
            oidx += (size_t)16 * 1024 * 32;   // i += 16 -> 524,288 f4
        }
    }
}

extern "C" void kernel_launch(void* const* d_in, const int* in_sizes, int n_in,
                              void* d_out, int out_size, void* d_ws, size_t ws_size,
                              hipStream_t stream) {
    const int*   asym  = (const int*)  d_in[0];
    const int*   resid = (const int*)  d_in[1];
    const int*   ent   = (const int*)  d_in[2];
    const int*   tok   = (const int*)  d_in[3];
    const int*   sym   = (const int*)  d_in[4];
    const float* W     = (const float*)d_in[5];
    f4* outv = (f4*)d_out;

    relpos_kernel<<<GRID, THREADS, 0, stream>>>(asym, resid, ent, tok, sym, W, outv);
}